// Round 2
// baseline (851.162 us; speedup 1.0000x reference)
//
#include <hip/hip_runtime.h>
#include <hip/hip_bf16.h>

// Problem constants (reference: B=2, N=4096, D=1024, K=256)
#define B_  2
#define N_  4096
#define D_  1024
#define K_  256
#define NC_ 512   // 2*K_ : [CL | CR] concatenated columns

typedef __bf16 bf16;
typedef __bf16 bf16x8 __attribute__((ext_vector_type(8)));
typedef __bf16 bf16x4 __attribute__((ext_vector_type(4)));
typedef float  f32x4  __attribute__((ext_vector_type(4)));

#define MFMA(a, b, c) __builtin_amdgcn_mfma_f32_16x16x32_bf16(a, b, c, 0, 0, 0)

// ---------------------------------------------------------------------------
// K1: split x (fp32) into bf16 hi/lo, row-major AND transposed [B][D][N]
// ---------------------------------------------------------------------------
__global__ __launch_bounds__(256) void k_split_x(
    const float* __restrict__ x,
    bf16* __restrict__ xh,  bf16* __restrict__ xl,
    bf16* __restrict__ xth, bf16* __restrict__ xtl) {
  __shared__ bf16 th[32][33], tl[32][33];
  int r0 = blockIdx.x * 32;          // global row in [0, B*N)
  int d0 = blockIdx.y * 32;          // col in [0, D)
  int tc = threadIdx.x & 31, tr0 = threadIdx.x >> 5;
#pragma unroll
  for (int it = 0; it < 4; ++it) {
    int row = tr0 + it * 8;
    size_t idx = (size_t)(r0 + row) * D_ + d0 + tc;
    float f = x[idx];
    bf16 h = (bf16)f;
    bf16 l = (bf16)(f - (float)h);
    xh[idx] = h; xl[idx] = l;
    th[row][tc] = h; tl[row][tc] = l;
  }
  __syncthreads();
  int b = r0 >> 12;               // r0 / N_
  int i0 = r0 & (N_ - 1);
#pragma unroll
  for (int it = 0; it < 4; ++it) {
    int dr = tr0 + it * 8;
    size_t idx = (size_t)b * D_ * N_ + (size_t)(d0 + dr) * N_ + i0 + tc;
    xth[idx] = th[tc][dr];
    xtl[idx] = tl[tc][dr];
  }
}

// ---------------------------------------------------------------------------
// K2a: split+transpose [CL|CR] (each [D][K] fp32) -> CT hi/lo [NC][D] bf16
// ---------------------------------------------------------------------------
__global__ __launch_bounds__(256) void k_split_c(
    const float* __restrict__ cl, const float* __restrict__ cr,
    bf16* __restrict__ cth, bf16* __restrict__ ctl) {
  __shared__ bf16 th[32][33], tl[32][33];
  int c0 = blockIdx.x * 32;   // NC/32 = 16
  int k0 = blockIdx.y * 32;   // D/32 = 32
  int tc = threadIdx.x & 31, tr0 = threadIdx.x >> 5;
#pragma unroll
  for (int it = 0; it < 4; ++it) {
    int kk = tr0 + it * 8;
    int c = c0 + tc;
    float f = (c < K_) ? cl[(size_t)(k0 + kk) * K_ + c]
                       : cr[(size_t)(k0 + kk) * K_ + (c - K_)];
    bf16 h = (bf16)f;
    bf16 l = (bf16)(f - (float)h);
    th[kk][tc] = h; tl[kk][tc] = l;
  }
  __syncthreads();
#pragma unroll
  for (int it = 0; it < 4; ++it) {
    int cc = tr0 + it * 8;
    size_t idx = (size_t)(c0 + cc) * D_ + k0 + tc;
    cth[idx] = th[tc][cc];
    ctl[idx] = tl[tc][cc];
  }
}

// ---------------------------------------------------------------------------
// K2: projection GEMM  [B*N, D] @ [D, NC] -> L,R stored as bf16 hi/lo [B*N][K]
// 3-product split MFMA: Ah*Bh + Al*Bh + Ah*Bl  (near-fp32 precision)
// 128x128 tile, 4 waves (2x2), wave tile 64x64
// ---------------------------------------------------------------------------
__global__ __launch_bounds__(256) void k_proj(
    const bf16* __restrict__ xh, const bf16* __restrict__ xl,
    const bf16* __restrict__ cth, const bf16* __restrict__ ctl,
    bf16* __restrict__ lh, bf16* __restrict__ ll,
    bf16* __restrict__ rh, bf16* __restrict__ rl) {
  int tid = threadIdx.x, lane = tid & 63, wid = tid >> 6;
  int wm = wid >> 1, wn = wid & 1;
  int lr = lane & 15, lg = lane >> 4;
  int row0 = blockIdx.x * 128 + wm * 64;
  int col0 = blockIdx.y * 128 + wn * 64;
  f32x4 acc[4][4] = {};
  for (int ks = 0; ks < 32; ++ks) {
    int k = ks * 32 + lg * 8;
    bf16x8 Ah[4], Al[4], Bh[4], Bl[4];
#pragma unroll
    for (int mi = 0; mi < 4; ++mi) {
      size_t off = (size_t)(row0 + mi * 16 + lr) * D_ + k;
      Ah[mi] = *(const bf16x8*)(xh + off);
      Al[mi] = *(const bf16x8*)(xl + off);
    }
#pragma unroll
    for (int ni = 0; ni < 4; ++ni) {
      size_t off = (size_t)(col0 + ni * 16 + lr) * D_ + k;
      Bh[ni] = *(const bf16x8*)(cth + off);
      Bl[ni] = *(const bf16x8*)(ctl + off);
    }
#pragma unroll
    for (int mi = 0; mi < 4; ++mi)
#pragma unroll
      for (int ni = 0; ni < 4; ++ni) {
        acc[mi][ni] = MFMA(Ah[mi], Bh[ni], acc[mi][ni]);
        acc[mi][ni] = MFMA(Al[mi], Bh[ni], acc[mi][ni]);
        acc[mi][ni] = MFMA(Ah[mi], Bl[ni], acc[mi][ni]);
      }
  }
#pragma unroll
  for (int mi = 0; mi < 4; ++mi)
#pragma unroll
    for (int ni = 0; ni < 4; ++ni)
#pragma unroll
      for (int r = 0; r < 4; ++r) {
        int row = row0 + mi * 16 + lg * 4 + r;   // C/D: col=lane&15, row=(lane>>4)*4+r
        int col = col0 + ni * 16 + lr;
        float v = acc[mi][ni][r];
        bf16 h = (bf16)v;
        bf16 l = (bf16)(v - (float)h);
        if (col < K_) {
          lh[(size_t)row * K_ + col] = h;  ll[(size_t)row * K_ + col] = l;
        } else {
          rh[(size_t)row * K_ + col - K_] = h;  rl[(size_t)row * K_ + col - K_] = l;
        }
      }
}

// ---------------------------------------------------------------------------
// K3: S = (L @ R^T) / sqrt(D), fp32 out [B][N][N].  3-product split MFMA.
// 128x128 tile, 4 waves (2x2), K-dim = 256 (8 steps of 32)
// ---------------------------------------------------------------------------
__global__ __launch_bounds__(256) void k_qk(
    const bf16* __restrict__ lh, const bf16* __restrict__ ll,
    const bf16* __restrict__ rh, const bf16* __restrict__ rl,
    float* __restrict__ S) {
  int tid = threadIdx.x, lane = tid & 63, wid = tid >> 6;
  int wm = wid >> 1, wn = wid & 1;
  int lr = lane & 15, lg = lane >> 4;
  int b = blockIdx.z;
  int i0 = blockIdx.x * 128 + wm * 64;
  int j0 = blockIdx.y * 128 + wn * 64;
  const bf16* lhb = lh + (size_t)b * N_ * K_;
  const bf16* llb = ll + (size_t)b * N_ * K_;
  const bf16* rhb = rh + (size_t)b * N_ * K_;
  const bf16* rlb = rl + (size_t)b * N_ * K_;
  f32x4 acc[4][4] = {};
#pragma unroll
  for (int ks = 0; ks < 8; ++ks) {
    int k = ks * 32 + lg * 8;
    bf16x8 Ah[4], Al[4], Bh[4], Bl[4];
#pragma unroll
    for (int mi = 0; mi < 4; ++mi) {
      size_t off = (size_t)(i0 + mi * 16 + lr) * K_ + k;
      Ah[mi] = *(const bf16x8*)(lhb + off);
      Al[mi] = *(const bf16x8*)(llb + off);
    }
#pragma unroll
    for (int ni = 0; ni < 4; ++ni) {
      size_t off = (size_t)(j0 + ni * 16 + lr) * K_ + k;
      Bh[ni] = *(const bf16x8*)(rhb + off);
      Bl[ni] = *(const bf16x8*)(rlb + off);
    }
#pragma unroll
    for (int mi = 0; mi < 4; ++mi)
#pragma unroll
      for (int ni = 0; ni < 4; ++ni) {
        acc[mi][ni] = MFMA(Ah[mi], Bh[ni], acc[mi][ni]);
        acc[mi][ni] = MFMA(Al[mi], Bh[ni], acc[mi][ni]);
        acc[mi][ni] = MFMA(Ah[mi], Bl[ni], acc[mi][ni]);
      }
  }
  float* Sb = S + (size_t)b * N_ * N_;
  const float sc = 0.03125f;   // 1/sqrt(1024)
#pragma unroll
  for (int mi = 0; mi < 4; ++mi)
#pragma unroll
    for (int ni = 0; ni < 4; ++ni)
#pragma unroll
      for (int r = 0; r < 4; ++r) {
        int row = i0 + mi * 16 + lg * 4 + r;
        int col = j0 + ni * 16 + lr;
        Sb[(size_t)row * N_ + col] = acc[mi][ni][r] * sc;
      }
}

// ---------------------------------------------------------------------------
// K4: per-row softmax stats over ALL columns: m = max(S), invl = 1/sum exp(S-m)
// one 256-thread block per row (B*N rows); gate_bias cancels in softmax.
// ---------------------------------------------------------------------------
__global__ __launch_bounds__(256) void k_stats(
    const float* __restrict__ S, float2* __restrict__ stats) {
  int row = blockIdx.x;
  const float* sr = S + (size_t)row * N_;
  int tid = threadIdx.x;
  float4 v[4];
  float m = -3.4e38f;
#pragma unroll
  for (int it = 0; it < 4; ++it) {
    v[it] = *(const float4*)(sr + it * 1024 + tid * 4);
    m = fmaxf(m, fmaxf(fmaxf(v[it].x, v[it].y), fmaxf(v[it].z, v[it].w)));
  }
#pragma unroll
  for (int o = 32; o; o >>= 1) m = fmaxf(m, __shfl_xor(m, o, 64));
  __shared__ float wm_[4], ws_[4];
  int lane = tid & 63, wid = tid >> 6;
  if (lane == 0) wm_[wid] = m;
  __syncthreads();
  m = fmaxf(fmaxf(wm_[0], wm_[1]), fmaxf(wm_[2], wm_[3]));
  float l = 0.f;
#pragma unroll
  for (int it = 0; it < 4; ++it)
    l += expf(v[it].x - m) + expf(v[it].y - m) + expf(v[it].z - m) + expf(v[it].w - m);
#pragma unroll
  for (int o = 32; o; o >>= 1) l += __shfl_xor(l, o, 64);
  if (lane == 0) ws_[wid] = l;
  __syncthreads();
  if (tid == 0) {
    l = ws_[0] + ws_[1] + ws_[2] + ws_[3];
    stats[row] = make_float2(m, 1.0f / l);
  }
}

// ---------------------------------------------------------------------------
// K5: out = (mask(S) * exp(S - m) / l) @ x
// Block: 64 rows x 512 d-cols, 512 threads = 8 waves (2 M x 4 D),
// wave tile 32x128. Per 32-j step: all threads compute P hi/lo into LDS,
// then MFMA 3-product with V fragments from transposed x (hi/lo).
// ---------------------------------------------------------------------------
__global__ __launch_bounds__(512) void k_out(
    const float* __restrict__ S, const float2* __restrict__ stats,
    const bf16* __restrict__ xth, const bf16* __restrict__ xtl,
    const float* __restrict__ thrp, float* __restrict__ out) {
  __shared__ bf16 Ph[64][40], Pl[64][40];   // +8 pad -> 80B row stride, 2-way-bank-free
  __shared__ float sinvl[64];
  int tid = threadIdx.x;
  int b  = blockIdx.z;
  int i0 = blockIdx.x * 64;
  int d0 = blockIdx.y * 512;
  size_t row0 = (size_t)b * N_ + i0;       // global row into S/stats/out
  float thr = *thrp;
  if (tid < 64) sinvl[tid] = stats[row0 + tid].y;
  int prow = tid >> 3;                      // 0..63 (P-phase row)
  int jq = (tid & 7) * 4;                   // 0..28 (P-phase j offset)
  float m_row = stats[row0 + prow].x;
  const float* srow = S + (row0 + prow) * (size_t)N_;
  int lane = tid & 63, wid = tid >> 6;
  int wm = wid >> 2, wd = wid & 3;
  int lr = lane & 15, lg = lane >> 4;
  const bf16* vhb = xth + (size_t)b * D_ * N_;
  const bf16* vlb = xtl + (size_t)b * D_ * N_;
  f32x4 acc[2][8] = {};
  __syncthreads();
  for (int j = 0; j < N_; j += 32) {
    // --- P phase: numerator weights = mask * exp(S - m); split to bf16 hi/lo
    float4 s4 = *(const float4*)(srow + j + jq);
    float p0 = (s4.x > thr) ? expf(s4.x - m_row) : 0.f;
    float p1 = (s4.y > thr) ? expf(s4.y - m_row) : 0.f;
    float p2 = (s4.z > thr) ? expf(s4.z - m_row) : 0.f;
    float p3 = (s4.w > thr) ? expf(s4.w - m_row) : 0.f;
    bf16 h0 = (bf16)p0, h1 = (bf16)p1, h2 = (bf16)p2, h3 = (bf16)p3;
    bf16 l0 = (bf16)(p0 - (float)h0), l1 = (bf16)(p1 - (float)h1);
    bf16 l2 = (bf16)(p2 - (float)h2), l3 = (bf16)(p3 - (float)h3);
    *(bf16x4*)&Ph[prow][jq] = (bf16x4){h0, h1, h2, h3};
    *(bf16x4*)&Pl[prow][jq] = (bf16x4){l0, l1, l2, l3};
    __syncthreads();
    // --- MFMA phase
    bf16x8 pah[2], pal[2];
#pragma unroll
    for (int mf = 0; mf < 2; ++mf) {
      pah[mf] = *(const bf16x8*)&Ph[wm * 32 + mf * 16 + lr][lg * 8];
      pal[mf] = *(const bf16x8*)&Pl[wm * 32 + mf * 16 + lr][lg * 8];
    }
#pragma unroll
    for (int df = 0; df < 8; ++df) {
      int d = d0 + wd * 128 + df * 16 + lr;
      size_t voff = (size_t)d * N_ + j + lg * 8;
      bf16x8 vh = *(const bf16x8*)(vhb + voff);
      bf16x8 vl = *(const bf16x8*)(vlb + voff);
#pragma unroll
      for (int mf = 0; mf < 2; ++mf) {
        acc[mf][df] = MFMA(pah[mf], vh, acc[mf][df]);
        acc[mf][df] = MFMA(pal[mf], vh, acc[mf][df]);
        acc[mf][df] = MFMA(pah[mf], vl, acc[mf][df]);
      }
    }
    __syncthreads();
  }
  // --- epilogue: scale by 1/l per row, store fp32
#pragma unroll
  for (int mf = 0; mf < 2; ++mf)
#pragma unroll
    for (int r = 0; r < 4; ++r) {
      int rl_ = wm * 32 + mf * 16 + lg * 4 + r;
      float il = sinvl[rl_];
      size_t obase = (row0 + rl_) * (size_t)D_;
#pragma unroll
      for (int df = 0; df < 8; ++df) {
        int d = d0 + wd * 128 + df * 16 + lr;
        out[obase + d] = acc[mf][df][r] * il;
      }
    }
}

// ---------------------------------------------------------------------------
extern "C" void kernel_launch(void* const* d_in, const int* in_sizes, int n_in,
                              void* d_out, int out_size, void* d_ws, size_t ws_size,
                              hipStream_t stream) {
  const float* x   = (const float*)d_in[0];
  const float* cl  = (const float*)d_in[1];
  const float* cr  = (const float*)d_in[2];
  const float* thr = (const float*)d_in[3];
  // d_in[4] = gate_bias: uniform shift cancels in softmax -> unused.
  float* out = (float*)d_out;

  char* w = (char*)d_ws;
  size_t off = 0;
  auto alloc = [&](size_t bytes) -> char* {
    char* p = w + off;
    off += (bytes + 255) & ~(size_t)255;
    return p;
  };
  const size_t XE = (size_t)B_ * N_ * D_;   // 8388608
  bf16* xh  = (bf16*)alloc(XE * 2);
  bf16* xl  = (bf16*)alloc(XE * 2);
  bf16* xth = (bf16*)alloc(XE * 2);
  bf16* xtl = (bf16*)alloc(XE * 2);
  bf16* cth = (bf16*)alloc((size_t)NC_ * D_ * 2);
  bf16* ctl = (bf16*)alloc((size_t)NC_ * D_ * 2);
  bf16* lh  = (bf16*)alloc((size_t)B_ * N_ * K_ * 2);
  bf16* ll  = (bf16*)alloc((size_t)B_ * N_ * K_ * 2);
  bf16* rh  = (bf16*)alloc((size_t)B_ * N_ * K_ * 2);
  bf16* rl  = (bf16*)alloc((size_t)B_ * N_ * K_ * 2);
  float2* stats = (float2*)alloc((size_t)B_ * N_ * sizeof(float2));
  float* S  = (float*)alloc((size_t)B_ * N_ * N_ * 4);   // 128 MB
  // total ws use ~210 MB

  k_split_x<<<dim3((B_ * N_) / 32, D_ / 32), 256, 0, stream>>>(x, xh, xl, xth, xtl);
  k_split_c<<<dim3(NC_ / 32, D_ / 32), 256, 0, stream>>>(cl, cr, cth, ctl);
  k_proj<<<dim3((B_ * N_) / 128, NC_ / 128), 256, 0, stream>>>(xh, xl, cth, ctl, lh, ll, rh, rl);
  k_qk<<<dim3(N_ / 128, N_ / 128, B_), 256, 0, stream>>>(lh, ll, rh, rl, S);
  k_stats<<<B_ * N_, 256, 0, stream>>>(S, stats);
  k_out<<<dim3(N_ / 64, D_ / 512, B_), 512, 0, stream>>>(S, stats, xth, xtl, thr, out);
}

// Round 7
// 432.562 us; speedup vs baseline: 1.9677x; 1.9677x over previous
//
#include <hip/hip_runtime.h>
#include <hip/hip_bf16.h>

// Problem constants (reference: B=2, N=4096, D=1024, K=256)
#define B_  2
#define N_  4096
#define D_  1024
#define K_  256
#define NC_ 512   // 2*K_ : [CL | CR] concatenated columns

typedef __bf16 bf16;
typedef __bf16 bf16x8 __attribute__((ext_vector_type(8)));
typedef __bf16 bf16x4 __attribute__((ext_vector_type(4)));
typedef float  f32x4  __attribute__((ext_vector_type(4)));

#define MFMA(a, b, c) __builtin_amdgcn_mfma_f32_16x16x32_bf16(a, b, c, 0, 0, 0)

// async global->LDS, 16B per lane; lds base must be wave-uniform (HW adds lane*16)
__device__ __forceinline__ void gload_lds16(const void* g, void* s) {
  __builtin_amdgcn_global_load_lds((const __attribute__((address_space(1))) void*)g,
                                   (__attribute__((address_space(3))) void*)s,
                                   16, 0, 0);
}

// ---------------------------------------------------------------------------
// K1: split x (fp32) into bf16 hi/lo row-major, + bf16 hi transposed [B][D][N]
// ---------------------------------------------------------------------------
__global__ __launch_bounds__(256) void k_split_x(
    const float* __restrict__ x,
    bf16* __restrict__ xh,  bf16* __restrict__ xl,
    bf16* __restrict__ xth) {
  __shared__ bf16 th[32][33];
  int r0 = blockIdx.x * 32;          // global row in [0, B*N)
  int d0 = blockIdx.y * 32;          // col in [0, D)
  int tc = threadIdx.x & 31, tr0 = threadIdx.x >> 5;
#pragma unroll
  for (int it = 0; it < 4; ++it) {
    int row = tr0 + it * 8;
    size_t idx = (size_t)(r0 + row) * D_ + d0 + tc;
    float f = x[idx];
    bf16 h = (bf16)f;
    bf16 l = (bf16)(f - (float)h);
    xh[idx] = h; xl[idx] = l;
    th[row][tc] = h;
  }
  __syncthreads();
  int b = r0 >> 12;               // r0 / N_
  int i0 = r0 & (N_ - 1);
#pragma unroll
  for (int it = 0; it < 4; ++it) {
    int dr = tr0 + it * 8;
    size_t idx = (size_t)b * D_ * N_ + (size_t)(d0 + dr) * N_ + i0 + tc;
    xth[idx] = th[tc][dr];
  }
}

// ---------------------------------------------------------------------------
// K2a: split+transpose [CL|CR] (each [D][K] fp32) -> CT hi/lo [NC][D] bf16
// ---------------------------------------------------------------------------
__global__ __launch_bounds__(256) void k_split_c(
    const float* __restrict__ cl, const float* __restrict__ cr,
    bf16* __restrict__ cth, bf16* __restrict__ ctl) {
  __shared__ bf16 th[32][33], tl[32][33];
  int c0 = blockIdx.x * 32;   // NC/32 = 16
  int k0 = blockIdx.y * 32;   // D/32 = 32
  int tc = threadIdx.x & 31, tr0 = threadIdx.x >> 5;
#pragma unroll
  for (int it = 0; it < 4; ++it) {
    int kk = tr0 + it * 8;
    int c = c0 + tc;
    float f = (c < K_) ? cl[(size_t)(k0 + kk) * K_ + c]
                       : cr[(size_t)(k0 + kk) * K_ + (c - K_)];
    bf16 h = (bf16)f;
    bf16 l = (bf16)(f - (float)h);
    th[kk][tc] = h; tl[kk][tc] = l;
  }
  __syncthreads();
#pragma unroll
  for (int it = 0; it < 4; ++it) {
    int cc = tr0 + it * 8;
    size_t idx = (size_t)(c0 + cc) * D_ + k0 + tc;
    cth[idx] = th[tc][cc];
    ctl[idx] = tl[tc][cc];
  }
}

// ---------------------------------------------------------------------------
// K2: projection GEMM  [B*N, D] @ [D, NC] -> L,R stored as bf16 hi/lo [B*N][K]
// 3-product split MFMA: Ah*Bh + Al*Bh + Ah*Bl  (near-fp32 precision)
// ---------------------------------------------------------------------------
__global__ __launch_bounds__(256) void k_proj(
    const bf16* __restrict__ xh, const bf16* __restrict__ xl,
    const bf16* __restrict__ cth, const bf16* __restrict__ ctl,
    bf16* __restrict__ lh, bf16* __restrict__ ll,
    bf16* __restrict__ rh, bf16* __restrict__ rl) {
  int tid = threadIdx.x, lane = tid & 63, wid = tid >> 6;
  int wm = wid >> 1, wn = wid & 1;
  int lr = lane & 15, lg = lane >> 4;
  int row0 = blockIdx.x * 128 + wm * 64;
  int col0 = blockIdx.y * 128 + wn * 64;
  f32x4 acc[4][4] = {};
  for (int ks = 0; ks < 32; ++ks) {
    int k = ks * 32 + lg * 8;
    bf16x8 Ah[4], Al[4], Bh[4], Bl[4];
#pragma unroll
    for (int mi = 0; mi < 4; ++mi) {
      size_t off = (size_t)(row0 + mi * 16 + lr) * D_ + k;
      Ah[mi] = *(const bf16x8*)(xh + off);
      Al[mi] = *(const bf16x8*)(xl + off);
    }
#pragma unroll
    for (int ni = 0; ni < 4; ++ni) {
      size_t off = (size_t)(col0 + ni * 16 + lr) * D_ + k;
      Bh[ni] = *(const bf16x8*)(cth + off);
      Bl[ni] = *(const bf16x8*)(ctl + off);
    }
#pragma unroll
    for (int mi = 0; mi < 4; ++mi)
#pragma unroll
      for (int ni = 0; ni < 4; ++ni) {
        acc[mi][ni] = MFMA(Ah[mi], Bh[ni], acc[mi][ni]);
        acc[mi][ni] = MFMA(Al[mi], Bh[ni], acc[mi][ni]);
        acc[mi][ni] = MFMA(Ah[mi], Bl[ni], acc[mi][ni]);
      }
  }
#pragma unroll
  for (int mi = 0; mi < 4; ++mi)
#pragma unroll
    for (int ni = 0; ni < 4; ++ni)
#pragma unroll
      for (int r = 0; r < 4; ++r) {
        int row = row0 + mi * 16 + lg * 4 + r;   // C/D: col=lane&15, row=(lane>>4)*4+r
        int col = col0 + ni * 16 + lr;
        float v = acc[mi][ni][r];
        bf16 h = (bf16)v;
        bf16 l = (bf16)(v - (float)h);
        if (col < K_) {
          lh[(size_t)row * K_ + col] = h;  ll[(size_t)row * K_ + col] = l;
        } else {
          rh[(size_t)row * K_ + col - K_] = h;  rl[(size_t)row * K_ + col - K_] = l;
        }
      }
}

// ---------------------------------------------------------------------------
// K3: S = (L @ R^T) / sqrt(D), fp32 out [B][N][N].  3-product split MFMA.
// ---------------------------------------------------------------------------
__global__ __launch_bounds__(256) void k_qk(
    const bf16* __restrict__ lh, const bf16* __restrict__ ll,
    const bf16* __restrict__ rh, const bf16* __restrict__ rl,
    float* __restrict__ S) {
  int tid = threadIdx.x, lane = tid & 63, wid = tid >> 6;
  int wm = wid >> 1, wn = wid & 1;
  int lr = lane & 15, lg = lane >> 4;
  int b = blockIdx.z;
  int i0 = blockIdx.x * 128 + wm * 64;
  int j0 = blockIdx.y * 128 + wn * 64;
  const bf16* lhb = lh + (size_t)b * N_ * K_;
  const bf16* llb = ll + (size_t)b * N_ * K_;
  const bf16* rhb = rh + (size_t)b * N_ * K_;
  const bf16* rlb = rl + (size_t)b * N_ * K_;
  f32x4 acc[4][4] = {};
#pragma unroll
  for (int ks = 0; ks < 8; ++ks) {
    int k = ks * 32 + lg * 8;
    bf16x8 Ah[4], Al[4], Bh[4], Bl[4];
#pragma unroll
    for (int mi = 0; mi < 4; ++mi) {
      size_t off = (size_t)(i0 + mi * 16 + lr) * K_ + k;
      Ah[mi] = *(const bf16x8*)(lhb + off);
      Al[mi] = *(const bf16x8*)(llb + off);
    }
#pragma unroll
    for (int ni = 0; ni < 4; ++ni) {
      size_t off = (size_t)(j0 + ni * 16 + lr) * K_ + k;
      Bh[ni] = *(const bf16x8*)(rhb + off);
      Bl[ni] = *(const bf16x8*)(rlb + off);
    }
#pragma unroll
    for (int mi = 0; mi < 4; ++mi)
#pragma unroll
      for (int ni = 0; ni < 4; ++ni) {
        acc[mi][ni] = MFMA(Ah[mi], Bh[ni], acc[mi][ni]);
        acc[mi][ni] = MFMA(Al[mi], Bh[ni], acc[mi][ni]);
        acc[mi][ni] = MFMA(Ah[mi], Bl[ni], acc[mi][ni]);
      }
  }
  float* Sb = S + (size_t)b * N_ * N_;
  const float sc = 0.03125f;   // 1/sqrt(1024)
#pragma unroll
  for (int mi = 0; mi < 4; ++mi)
#pragma unroll
    for (int ni = 0; ni < 4; ++ni)
#pragma unroll
      for (int r = 0; r < 4; ++r) {
        int row = i0 + mi * 16 + lg * 4 + r;
        int col = j0 + ni * 16 + lr;
        Sb[(size_t)row * N_ + col] = acc[mi][ni][r] * sc;
      }
}

// ---------------------------------------------------------------------------
// K4: fused row stats + P materialization.
// One 256-thread block per row: row lives in registers (16 f32/thread).
// m = max(S), l = sum exp(S-m); P = (S>thr) ? exp(S-m)/l : 0  -> bf16.
// invl folded into P so the PV GEMM needs no epilogue scaling.
// ---------------------------------------------------------------------------
__global__ __launch_bounds__(256) void k_stats_p(
    const float* __restrict__ S, const float* __restrict__ thrp,
    bf16* __restrict__ P) {
  int row = blockIdx.x;
  const float* sr = S + (size_t)row * N_;
  bf16* pr = P + (size_t)row * N_;
  int tid = threadIdx.x;
  float thr = *thrp;
  float4 v[4];
  float m = -3.4e38f;
#pragma unroll
  for (int it = 0; it < 4; ++it) {
    v[it] = *(const float4*)(sr + it * 1024 + tid * 4);
    m = fmaxf(m, fmaxf(fmaxf(v[it].x, v[it].y), fmaxf(v[it].z, v[it].w)));
  }
#pragma unroll
  for (int o = 32; o; o >>= 1) m = fmaxf(m, __shfl_xor(m, o, 64));
  __shared__ float wm_[4], ws_[4];
  __shared__ float sm, sil;
  int lane = tid & 63, wid = tid >> 6;
  if (lane == 0) wm_[wid] = m;
  __syncthreads();
  m = fmaxf(fmaxf(wm_[0], wm_[1]), fmaxf(wm_[2], wm_[3]));
  float l = 0.f;
#pragma unroll
  for (int it = 0; it < 4; ++it)
    l += __expf(v[it].x - m) + __expf(v[it].y - m) +
         __expf(v[it].z - m) + __expf(v[it].w - m);
#pragma unroll
  for (int o = 32; o; o >>= 1) l += __shfl_xor(l, o, 64);
  if (lane == 0) ws_[wid] = l;
  __syncthreads();
  if (tid == 0) {
    float lt = ws_[0] + ws_[1] + ws_[2] + ws_[3];
    sm = m; sil = 1.0f / lt;
  }
  __syncthreads();
  float mm = sm, il = sil;
#pragma unroll
  for (int it = 0; it < 4; ++it) {
    float p0 = (v[it].x > thr) ? __expf(v[it].x - mm) * il : 0.f;
    float p1 = (v[it].y > thr) ? __expf(v[it].y - mm) * il : 0.f;
    float p2 = (v[it].z > thr) ? __expf(v[it].z - mm) * il : 0.f;
    float p3 = (v[it].w > thr) ? __expf(v[it].w - mm) * il : 0.f;
    *(bf16x4*)(pr + it * 1024 + tid * 4) = (bf16x4){(bf16)p0, (bf16)p1, (bf16)p2, (bf16)p3};
  }
}

// ---------------------------------------------------------------------------
// K5: out = P @ V   (pure bf16, m97 structure)
// A = P [N][N] bf16 (j-contiguous), B = VT [D][N] bf16 (j-contiguous) -> B^T GEMM.
// 128x128 tile, BK=32, 4 waves (2x2), double-buffered LDS via global_load_lds,
// one barrier per K-step (stage next || compute current).
// ---------------------------------------------------------------------------
__global__ __launch_bounds__(256) void k_pv(
    const bf16* __restrict__ P, const bf16* __restrict__ VT,
    float* __restrict__ out) {
  __shared__ bf16 sA[2][128 * 32], sB[2][128 * 32];
  int tid = threadIdx.x, lane = tid & 63, wid = tid >> 6;
  int b = blockIdx.z;
  int i0 = blockIdx.x * 128, d0 = blockIdx.y * 128;
  const bf16* Ab = P + (size_t)b * N_ * N_;
  const bf16* Bb = VT + (size_t)b * D_ * N_;
  int wm = wid >> 1, wn = wid & 1;
  int lr = lane & 15, lg = lane >> 4;
  // staging: per array 8KB = 4 waves x 2 issues of 1KB (16 rows x 64B)
  int srow = (lane >> 2);        // 0..15 within chunk
  int scol = (lane & 3) * 8;     // element offset within row

  f32x4 acc[4][4] = {};
  int cur = 0;

  // prologue: stage k-step 0
#pragma unroll
  for (int q = 0; q < 2; ++q) {
    int chunk = wid * 2 + q;
    gload_lds16(Ab + (size_t)(i0 + chunk * 16 + srow) * N_ + scol,
                &sA[0][chunk * 512]);
    gload_lds16(Bb + (size_t)(d0 + chunk * 16 + srow) * N_ + scol,
                &sB[0][chunk * 512]);
  }
  __syncthreads();

  for (int t = 0; t < N_ / 32; ++t) {
    if (t + 1 < N_ / 32) {
      int kk = (t + 1) * 32;
#pragma unroll
      for (int q = 0; q < 2; ++q) {
        int chunk = wid * 2 + q;
        gload_lds16(Ab + (size_t)(i0 + chunk * 16 + srow) * N_ + kk + scol,
                    &sA[cur ^ 1][chunk * 512]);
        gload_lds16(Bb + (size_t)(d0 + chunk * 16 + srow) * N_ + kk + scol,
                    &sB[cur ^ 1][chunk * 512]);
      }
    }
    bf16x8 Af[4], Bf[4];
#pragma unroll
    for (int mi = 0; mi < 4; ++mi)
      Af[mi] = *(const bf16x8*)&sA[cur][(wm * 64 + mi * 16 + lr) * 32 + lg * 8];
#pragma unroll
    for (int ni = 0; ni < 4; ++ni)
      Bf[ni] = *(const bf16x8*)&sB[cur][(wn * 64 + ni * 16 + lr) * 32 + lg * 8];
#pragma unroll
    for (int mi = 0; mi < 4; ++mi)
#pragma unroll
      for (int ni = 0; ni < 4; ++ni)
        acc[mi][ni] = MFMA(Af[mi], Bf[ni], acc[mi][ni]);
    __syncthreads();   // drains staged loads (vmcnt) + lds reads before buffer swap
    cur ^= 1;
  }

  float* ob = out + (size_t)b * N_ * D_;
#pragma unroll
  for (int mi = 0; mi < 4; ++mi)
#pragma unroll
    for (int ni = 0; ni < 4; ++ni)
#pragma unroll
      for (int r = 0; r < 4; ++r) {
        int row = i0 + wm * 64 + mi * 16 + lg * 4 + r;
        int col = d0 + wn * 64 + ni * 16 + lr;
        ob[(size_t)row * D_ + col] = acc[mi][ni][r];
      }
}

// ---------------------------------------------------------------------------
extern "C" void kernel_launch(void* const* d_in, const int* in_sizes, int n_in,
                              void* d_out, int out_size, void* d_ws, size_t ws_size,
                              hipStream_t stream) {
  const float* x   = (const float*)d_in[0];
  const float* cl  = (const float*)d_in[1];
  const float* cr  = (const float*)d_in[2];
  const float* thr = (const float*)d_in[3];
  // d_in[4] = gate_bias: uniform shift cancels in softmax -> unused.
  float* out = (float*)d_out;

  char* w = (char*)d_ws;
  size_t off = 0;
  auto alloc = [&](size_t bytes) -> char* {
    char* p = w + off;
    off += (bytes + 255) & ~(size_t)255;
    return p;
  };
  const size_t XE = (size_t)B_ * N_ * D_;    // 8388608
  const size_t LRE = (size_t)B_ * N_ * K_;   // 2097152
  // --- pool: dead after k_qk; P (64MB) aliases it ---------------------------
  char* pool = alloc(64ull << 20);
  bf16* xh = (bf16*)pool;                    // 16MB, dead after k_proj
  bf16* xl = (bf16*)(pool + (XE * 2));       // 16MB, dead after k_proj
  bf16* lh = (bf16*)(pool + (32ull << 20));                 // 4MB each,
  bf16* ll = (bf16*)(pool + (32ull << 20) + LRE * 2);       // dead after k_qk
  bf16* rh = (bf16*)(pool + (32ull << 20) + LRE * 4);
  bf16* rl = (bf16*)(pool + (32ull << 20) + LRE * 6);
  bf16* Ph = (bf16*)pool;                    // [B][N][N] bf16 = 64MB (aliases all above)
  // --- live-late buffers ----------------------------------------------------
  bf16* xth = (bf16*)alloc(XE * 2);                    // 16MB, live until k_pv
  bf16* cth = (bf16*)alloc((size_t)NC_ * D_ * 2);
  bf16* ctl = (bf16*)alloc((size_t)NC_ * D_ * 2);
  float* S  = (float*)alloc((size_t)B_ * N_ * N_ * 4); // 128MB
  // total ws use ~210MB

  k_split_x<<<dim3((B_ * N_) / 32, D_ / 32), 256, 0, stream>>>(x, xh, xl, xth);
  k_split_c<<<dim3(NC_ / 32, D_ / 32), 256, 0, stream>>>(cl, cr, cth, ctl);
  k_proj<<<dim3((B_ * N_) / 128, NC_ / 128), 256, 0, stream>>>(xh, xl, cth, ctl, lh, ll, rh, rl);
  k_qk<<<dim3(N_ / 128, N_ / 128, B_), 256, 0, stream>>>(lh, ll, rh, rl, S);
  k_stats_p<<<B_ * N_, 256, 0, stream>>>(S, thr, Ph);
  k_pv<<<dim3(N_ / 128, D_ / 128, B_), 256, 0, stream>>>(Ph, xth, out);
}

// Round 10
// 375.163 us; speedup vs baseline: 2.2688x; 1.1530x over previous
//
#include <hip/hip_runtime.h>
#include <hip/hip_bf16.h>

// Problem constants (reference: B=2, N=4096, D=1024, K=256)
#define B_  2
#define N_  4096
#define D_  1024
#define K_  256
#define NC_ 512   // 2*K_ : [CL | CR] concatenated columns

typedef __bf16 bf16;
typedef __bf16 bf16x8 __attribute__((ext_vector_type(8)));
typedef __bf16 bf16x4 __attribute__((ext_vector_type(4)));
typedef float  f32x4  __attribute__((ext_vector_type(4)));

#define MFMA(a, b, c) __builtin_amdgcn_mfma_f32_16x16x32_bf16(a, b, c, 0, 0, 0)

// async global->LDS, 16B per lane; lds base must be wave-uniform (HW adds lane*16)
__device__ __forceinline__ void gload_lds16(const void* g, void* s) {
  __builtin_amdgcn_global_load_lds((const __attribute__((address_space(1))) void*)g,
                                   (__attribute__((address_space(3))) void*)s,
                                   16, 0, 0);
}

// ---------------------------------------------------------------------------
// K1: split x (fp32) -> X2 [B*N][2048] = [xh | xl] bf16, + xth [B][D][N] (hi, T)
// ---------------------------------------------------------------------------
__global__ __launch_bounds__(256) void k_split_x(
    const float* __restrict__ x,
    bf16* __restrict__ X2, bf16* __restrict__ xth) {
  __shared__ bf16 th[32][33];
  int r0 = blockIdx.x * 32;          // global row in [0, B*N)
  int d0 = blockIdx.y * 32;          // col in [0, D)
  int tc = threadIdx.x & 31, tr0 = threadIdx.x >> 5;
#pragma unroll
  for (int it = 0; it < 4; ++it) {
    int row = tr0 + it * 8;
    size_t idx = (size_t)(r0 + row) * D_ + d0 + tc;
    float f = x[idx];
    bf16 h = (bf16)f;
    bf16 l = (bf16)(f - (float)h);
    size_t base = (size_t)(r0 + row) * 2048 + d0 + tc;
    X2[base] = h; X2[base + 1024] = l;
    th[row][tc] = h;
  }
  __syncthreads();
  int b = r0 >> 12;               // r0 / N_
  int i0 = r0 & (N_ - 1);
#pragma unroll
  for (int it = 0; it < 4; ++it) {
    int dr = tr0 + it * 8;
    size_t idx = (size_t)b * D_ * N_ + (size_t)(d0 + dr) * N_ + i0 + tc;
    xth[idx] = th[tc][dr];
  }
}

// ---------------------------------------------------------------------------
// K2a: split+transpose [CL|CR] (each [D][K] fp32) -> C2 [512][2048] = [Ch | Cl]
// row c of C2 = column c of [CL|CR], hi in k 0..1023, lo in 1024..2047
// ---------------------------------------------------------------------------
__global__ __launch_bounds__(256) void k_split_c(
    const float* __restrict__ cl, const float* __restrict__ cr,
    bf16* __restrict__ C2) {
  __shared__ bf16 th[32][33], tl[32][33];
  int c0 = blockIdx.x * 32;   // NC/32 = 16
  int k0 = blockIdx.y * 32;   // D/32 = 32
  int tc = threadIdx.x & 31, tr0 = threadIdx.x >> 5;
#pragma unroll
  for (int it = 0; it < 4; ++it) {
    int kk = tr0 + it * 8;
    int c = c0 + tc;
    float f = (c < K_) ? cl[(size_t)(k0 + kk) * K_ + c]
                       : cr[(size_t)(k0 + kk) * K_ + (c - K_)];
    bf16 h = (bf16)f;
    bf16 l = (bf16)(f - (float)h);
    th[kk][tc] = h; tl[kk][tc] = l;
  }
  __syncthreads();
#pragma unroll
  for (int it = 0; it < 4; ++it) {
    int cc = tr0 + it * 8;
    size_t base = (size_t)(c0 + cc) * 2048 + k0 + tc;
    C2[base] = th[tc][cc];
    C2[base + 1024] = tl[tc][cc];
  }
}

// ---------------------------------------------------------------------------
// K2: projection GEMM, m97 template over remapped K-axis (96 steps of 32):
//   t  0..31: xh * Ch   t 32..63: xl * Ch   t 64..95: xh * Cl
// A = X2 [8192][2048], B = C2 [512][2048]. Out: L2=[Lh|Ll], R2=[Rh|Rl] [8192][512]
// ---------------------------------------------------------------------------
__global__ __launch_bounds__(256) void k_proj(
    const bf16* __restrict__ X2, const bf16* __restrict__ C2,
    bf16* __restrict__ L2, bf16* __restrict__ R2) {
  __shared__ bf16 sA[2][128 * 32], sB[2][128 * 32];
  int tid = threadIdx.x, lane = tid & 63, wid = tid >> 6;
  int row0 = blockIdx.x * 128, col0 = blockIdx.y * 128;
  int wm = wid >> 1, wn = wid & 1;
  int lr = lane & 15, lg = lane >> 4;
  int srow = lane >> 2, scol = (lane & 3) * 8;
  f32x4 acc[4][4] = {};
  int cur = 0;
  const int NT = 96;
  // prologue: stage t=0 (aO=bO=0)
#pragma unroll
  for (int q = 0; q < 2; ++q) {
    int chunk = wid * 2 + q;
    gload_lds16(X2 + (size_t)(row0 + chunk * 16 + srow) * 2048 + scol, &sA[0][chunk * 512]);
    gload_lds16(C2 + (size_t)(col0 + chunk * 16 + srow) * 2048 + scol, &sB[0][chunk * 512]);
  }
  __syncthreads();
  for (int t = 0; t < NT; ++t) {
    if (t + 1 < NT) {
      int tn = t + 1, tm = tn & 31, grp = tn >> 5;
      int aO = tm * 32 + (grp == 1 ? 1024 : 0);
      int bO = tm * 32 + (grp == 2 ? 1024 : 0);
#pragma unroll
      for (int q = 0; q < 2; ++q) {
        int chunk = wid * 2 + q;
        gload_lds16(X2 + (size_t)(row0 + chunk * 16 + srow) * 2048 + aO + scol,
                    &sA[cur ^ 1][chunk * 512]);
        gload_lds16(C2 + (size_t)(col0 + chunk * 16 + srow) * 2048 + bO + scol,
                    &sB[cur ^ 1][chunk * 512]);
      }
    }
    bf16x8 Af[4], Bf[4];
#pragma unroll
    for (int mi = 0; mi < 4; ++mi)
      Af[mi] = *(const bf16x8*)&sA[cur][(wm * 64 + mi * 16 + lr) * 32 + lg * 8];
#pragma unroll
    for (int ni = 0; ni < 4; ++ni)
      Bf[ni] = *(const bf16x8*)&sB[cur][(wn * 64 + ni * 16 + lr) * 32 + lg * 8];
#pragma unroll
    for (int mi = 0; mi < 4; ++mi)
#pragma unroll
      for (int ni = 0; ni < 4; ++ni)
        acc[mi][ni] = MFMA(Af[mi], Bf[ni], acc[mi][ni]);
    __syncthreads();
    cur ^= 1;
  }
#pragma unroll
  for (int mi = 0; mi < 4; ++mi)
#pragma unroll
    for (int ni = 0; ni < 4; ++ni)
#pragma unroll
      for (int r = 0; r < 4; ++r) {
        int row = row0 + wm * 64 + mi * 16 + lg * 4 + r;
        int col = col0 + wn * 64 + ni * 16 + lr;
        float v = acc[mi][ni][r];
        bf16 h = (bf16)v;
        bf16 l = (bf16)(v - (float)h);
        if (col < K_) {
          L2[(size_t)row * 512 + col] = h;
          L2[(size_t)row * 512 + col + 256] = l;
        } else {
          R2[(size_t)row * 512 + col - 256] = h;
          R2[(size_t)row * 512 + col] = l;
        }
      }
}

// ---------------------------------------------------------------------------
// K3: S = 3-product split GEMM / sqrt(D), m97 template, remapped K (24 steps):
//   t 0..7: Lh*Rh   t 8..15: Ll*Rh   t 16..23: Lh*Rl
// A = L2 [N][512], B = R2 [N][512] per batch. Out S fp32 [N][N].
// ---------------------------------------------------------------------------
__global__ __launch_bounds__(256) void k_qk(
    const bf16* __restrict__ L2, const bf16* __restrict__ R2,
    float* __restrict__ S) {
  __shared__ bf16 sA[2][128 * 32], sB[2][128 * 32];
  int tid = threadIdx.x, lane = tid & 63, wid = tid >> 6;
  int b = blockIdx.z;
  int i0 = blockIdx.x * 128, j0 = blockIdx.y * 128;
  const bf16* Ab = L2 + (size_t)b * N_ * 512;
  const bf16* Bb = R2 + (size_t)b * N_ * 512;
  int wm = wid >> 1, wn = wid & 1;
  int lr = lane & 15, lg = lane >> 4;
  int srow = lane >> 2, scol = (lane & 3) * 8;
  f32x4 acc[4][4] = {};
  int cur = 0;
  const int NT = 24;
  // prologue: stage t=0 (aO=bO=0)
#pragma unroll
  for (int q = 0; q < 2; ++q) {
    int chunk = wid * 2 + q;
    gload_lds16(Ab + (size_t)(i0 + chunk * 16 + srow) * 512 + scol, &sA[0][chunk * 512]);
    gload_lds16(Bb + (size_t)(j0 + chunk * 16 + srow) * 512 + scol, &sB[0][chunk * 512]);
  }
  __syncthreads();
  for (int t = 0; t < NT; ++t) {
    if (t + 1 < NT) {
      int tn = t + 1, tm = tn & 7, grp = tn >> 3;
      int aO = tm * 32 + (grp == 1 ? 256 : 0);
      int bO = tm * 32 + (grp == 2 ? 256 : 0);
#pragma unroll
      for (int q = 0; q < 2; ++q) {
        int chunk = wid * 2 + q;
        gload_lds16(Ab + (size_t)(i0 + chunk * 16 + srow) * 512 + aO + scol,
                    &sA[cur ^ 1][chunk * 512]);
        gload_lds16(Bb + (size_t)(j0 + chunk * 16 + srow) * 512 + bO + scol,
                    &sB[cur ^ 1][chunk * 512]);
      }
    }
    bf16x8 Af[4], Bf[4];
#pragma unroll
    for (int mi = 0; mi < 4; ++mi)
      Af[mi] = *(const bf16x8*)&sA[cur][(wm * 64 + mi * 16 + lr) * 32 + lg * 8];
#pragma unroll
    for (int ni = 0; ni < 4; ++ni)
      Bf[ni] = *(const bf16x8*)&sB[cur][(wn * 64 + ni * 16 + lr) * 32 + lg * 8];
#pragma unroll
    for (int mi = 0; mi < 4; ++mi)
#pragma unroll
      for (int ni = 0; ni < 4; ++ni)
        acc[mi][ni] = MFMA(Af[mi], Bf[ni], acc[mi][ni]);
    __syncthreads();
    cur ^= 1;
  }
  float* Sb = S + (size_t)b * N_ * N_;
  const float sc = 0.03125f;   // 1/sqrt(1024)
#pragma unroll
  for (int mi = 0; mi < 4; ++mi)
#pragma unroll
    for (int ni = 0; ni < 4; ++ni)
#pragma unroll
      for (int r = 0; r < 4; ++r) {
        int row = i0 + wm * 64 + mi * 16 + lg * 4 + r;
        int col = j0 + wn * 64 + ni * 16 + lr;
        Sb[(size_t)row * N_ + col] = acc[mi][ni][r] * sc;
      }
}

// ---------------------------------------------------------------------------
// K4: fused row stats + P materialization.
// One 256-thread block per row: row lives in registers (16 f32/thread).
// m = max(S), l = sum exp(S-m); P = (S>thr) ? exp(S-m)/l : 0  -> bf16.
// ---------------------------------------------------------------------------
__global__ __launch_bounds__(256) void k_stats_p(
    const float* __restrict__ S, const float* __restrict__ thrp,
    bf16* __restrict__ P) {
  int row = blockIdx.x;
  const float* sr = S + (size_t)row * N_;
  bf16* pr = P + (size_t)row * N_;
  int tid = threadIdx.x;
  float thr = *thrp;
  float4 v[4];
  float m = -3.4e38f;
#pragma unroll
  for (int it = 0; it < 4; ++it) {
    v[it] = *(const float4*)(sr + it * 1024 + tid * 4);
    m = fmaxf(m, fmaxf(fmaxf(v[it].x, v[it].y), fmaxf(v[it].z, v[it].w)));
  }
#pragma unroll
  for (int o = 32; o; o >>= 1) m = fmaxf(m, __shfl_xor(m, o, 64));
  __shared__ float wm_[4], ws_[4];
  __shared__ float sm, sil;
  int lane = tid & 63, wid = tid >> 6;
  if (lane == 0) wm_[wid] = m;
  __syncthreads();
  m = fmaxf(fmaxf(wm_[0], wm_[1]), fmaxf(wm_[2], wm_[3]));
  float l = 0.f;
#pragma unroll
  for (int it = 0; it < 4; ++it)
    l += __expf(v[it].x - m) + __expf(v[it].y - m) +
         __expf(v[it].z - m) + __expf(v[it].w - m);
#pragma unroll
  for (int o = 32; o; o >>= 1) l += __shfl_xor(l, o, 64);
  if (lane == 0) ws_[wid] = l;
  __syncthreads();
  if (tid == 0) {
    float lt = ws_[0] + ws_[1] + ws_[2] + ws_[3];
    sm = m; sil = 1.0f / lt;
  }
  __syncthreads();
  float mm = sm, il = sil;
#pragma unroll
  for (int it = 0; it < 4; ++it) {
    float p0 = (v[it].x > thr) ? __expf(v[it].x - mm) * il : 0.f;
    float p1 = (v[it].y > thr) ? __expf(v[it].y - mm) * il : 0.f;
    float p2 = (v[it].z > thr) ? __expf(v[it].z - mm) * il : 0.f;
    float p3 = (v[it].w > thr) ? __expf(v[it].w - mm) * il : 0.f;
    *(bf16x4*)(pr + it * 1024 + tid * 4) = (bf16x4){(bf16)p0, (bf16)p1, (bf16)p2, (bf16)p3};
  }
}

// ---------------------------------------------------------------------------
// K5: out = P @ V   (pure bf16, m97 structure)  [unchanged, HW-validated]
// ---------------------------------------------------------------------------
__global__ __launch_bounds__(256) void k_pv(
    const bf16* __restrict__ P, const bf16* __restrict__ VT,
    float* __restrict__ out) {
  __shared__ bf16 sA[2][128 * 32], sB[2][128 * 32];
  int tid = threadIdx.x, lane = tid & 63, wid = tid >> 6;
  int b = blockIdx.z;
  int i0 = blockIdx.x * 128, d0 = blockIdx.y * 128;
  const bf16* Ab = P + (size_t)b * N_ * N_;
  const bf16* Bb = VT + (size_t)b * D_ * N_;
  int wm = wid >> 1, wn = wid & 1;
  int lr = lane & 15, lg = lane >> 4;
  int srow = (lane >> 2);
  int scol = (lane & 3) * 8;

  f32x4 acc[4][4] = {};
  int cur = 0;

#pragma unroll
  for (int q = 0; q < 2; ++q) {
    int chunk = wid * 2 + q;
    gload_lds16(Ab + (size_t)(i0 + chunk * 16 + srow) * N_ + scol, &sA[0][chunk * 512]);
    gload_lds16(Bb + (size_t)(d0 + chunk * 16 + srow) * N_ + scol, &sB[0][chunk * 512]);
  }
  __syncthreads();

  for (int t = 0; t < N_ / 32; ++t) {
    if (t + 1 < N_ / 32) {
      int kk = (t + 1) * 32;
#pragma unroll
      for (int q = 0; q < 2; ++q) {
        int chunk = wid * 2 + q;
        gload_lds16(Ab + (size_t)(i0 + chunk * 16 + srow) * N_ + kk + scol,
                    &sA[cur ^ 1][chunk * 512]);
        gload_lds16(Bb + (size_t)(d0 + chunk * 16 + srow) * N_ + kk + scol,
                    &sB[cur ^ 1][chunk * 512]);
      }
    }
    bf16x8 Af[4], Bf[4];
#pragma unroll
    for (int mi = 0; mi < 4; ++mi)
      Af[mi] = *(const bf16x8*)&sA[cur][(wm * 64 + mi * 16 + lr) * 32 + lg * 8];
#pragma unroll
    for (int ni = 0; ni < 4; ++ni)
      Bf[ni] = *(const bf16x8*)&sB[cur][(wn * 64 + ni * 16 + lr) * 32 + lg * 8];
#pragma unroll
    for (int mi = 0; mi < 4; ++mi)
#pragma unroll
      for (int ni = 0; ni < 4; ++ni)
        acc[mi][ni] = MFMA(Af[mi], Bf[ni], acc[mi][ni]);
    __syncthreads();
    cur ^= 1;
  }

  float* ob = out + (size_t)b * N_ * D_;
#pragma unroll
  for (int mi = 0; mi < 4; ++mi)
#pragma unroll
    for (int ni = 0; ni < 4; ++ni)
#pragma unroll
      for (int r = 0; r < 4; ++r) {
        int row = i0 + wm * 64 + mi * 16 + lg * 4 + r;
        int col = d0 + wn * 64 + ni * 16 + lr;
        ob[(size_t)row * D_ + col] = acc[mi][ni][r];
      }
}

// ---------------------------------------------------------------------------
extern "C" void kernel_launch(void* const* d_in, const int* in_sizes, int n_in,
                              void* d_out, int out_size, void* d_ws, size_t ws_size,
                              hipStream_t stream) {
  const float* x   = (const float*)d_in[0];
  const float* cl  = (const float*)d_in[1];
  const float* cr  = (const float*)d_in[2];
  const float* thr = (const float*)d_in[3];
  // d_in[4] = gate_bias: uniform shift cancels in softmax -> unused.
  float* out = (float*)d_out;

  char* w = (char*)d_ws;
  size_t off = 0;
  auto alloc = [&](size_t bytes) -> char* {
    char* p = w + off;
    off += (bytes + 255) & ~(size_t)255;
    return p;
  };
  const size_t XE = (size_t)B_ * N_ * D_;    // 8388608
  // --- pool (64MB): staged buffers, all dead before k_stats_p writes Ph -----
  char* pool = alloc(64ull << 20);
  bf16* X2 = (bf16*)pool;                       // [8192][2048] = 32MB, dead after k_proj
  bf16* L2 = (bf16*)(pool + (32ull << 20));     // [8192][512] = 8MB, dead after k_qk
  bf16* R2 = (bf16*)(pool + (40ull << 20));     // [8192][512] = 8MB, dead after k_qk
  bf16* Ph = (bf16*)pool;                       // [B][N][N] bf16 = 64MB (aliases all)
  // --- live-late buffers ----------------------------------------------------
  bf16* xth = (bf16*)alloc(XE * 2);                     // 16MB, live until k_pv
  bf16* C2  = (bf16*)alloc((size_t)NC_ * 2048 * 2);     // 2MB
  float* S  = (float*)alloc((size_t)B_ * N_ * N_ * 4);  // 128MB
  // total ws use ~210MB

  k_split_x<<<dim3((B_ * N_) / 32, D_ / 32), 256, 0, stream>>>(x, X2, xth);
  k_split_c<<<dim3(NC_ / 32, D_ / 32), 256, 0, stream>>>(cl, cr, C2);
  k_proj<<<dim3((B_ * N_) / 128, NC_ / 128), 256, 0, stream>>>(X2, C2, L2, R2);
  k_qk<<<dim3(N_ / 128, N_ / 128, B_), 256, 0, stream>>>(L2, R2, S);
  k_stats_p<<<B_ * N_, 256, 0, stream>>>(S, thr, Ph);
  k_pv<<<dim3(N_ / 128, D_ / 128, B_), 256, 0, stream>>>(Ph, xth, out);
}